// Round 4
// baseline (565.715 us; speedup 1.0000x reference)
//
#include <hip/hip_runtime.h>

#define DIM   384
#define HEADS 12
#define NTOK  49
#define NWIN  2048
#define NMASK 64
#define HD    32
#define MTOT  (NWIN * NTOK)   // 100352

typedef __bf16 bf16x8 __attribute__((ext_vector_type(8)));
typedef float  floatx4 __attribute__((ext_vector_type(4)));

__device__ __forceinline__ unsigned short f2bf(float f) {
  unsigned int u = __builtin_bit_cast(unsigned int, f);
  u += 0x7fffu + ((u >> 16) & 1u);   // RNE
  return (unsigned short)(u >> 16);
}
// pack 8 fp32 -> 8 bf16 via HW cvt (compiler emits v_cvt_pk_bf16_f32 pairs)
__device__ __forceinline__ uint4 cvt8(float4 a, float4 b) {
  union { uint4 u; __bf16 h[8]; } r;
  r.h[0] = (__bf16)a.x; r.h[1] = (__bf16)a.y;
  r.h[2] = (__bf16)a.z; r.h[3] = (__bf16)a.w;
  r.h[4] = (__bf16)b.x; r.h[5] = (__bf16)b.y;
  r.h[6] = (__bf16)b.z; r.h[7] = (__bf16)b.w;
  return r.u;
}
__device__ __forceinline__ void async_copy16(const void* g, void* l) {
  __builtin_amdgcn_global_load_lds((const __attribute__((address_space(1))) void*)g,
                                   (__attribute__((address_space(3))) void*)l, 16, 0, 0);
}

// ---------------------------------------------------------------------------
// prep: weight fp32->bf16 converts + lane-swizzled padded bias/mask tables.
// (x is consumed fp32 directly by the QKV gemm.)
// biasP[h][tile t][lane][reg] : r = (t>>2)*16 + (lane>>4)*4 + reg,
//                               c = (t&3)*16 + (lane&15); pad(-1e30) if r/c>=49
// maskP[g][...] identical layout.
// ---------------------------------------------------------------------------
__global__ void prep_kernel(const float* __restrict__ qkv_w,
                            const float* __restrict__ proj_w,
                            const float* __restrict__ rel_table,
                            const int*   __restrict__ rel_index,
                            const float* __restrict__ mask,
                            unsigned short* __restrict__ qkv_wb,
                            unsigned short* __restrict__ proj_wb,
                            float* __restrict__ biasP,
                            float* __restrict__ maskP) {
  const int tid  = blockIdx.x * blockDim.x + threadIdx.x;
  const int nthr = gridDim.x * blockDim.x;

  const int nw4 = (3 * DIM * DIM) / 4;
  for (int i = tid; i < nw4; i += nthr) {
    float4 v = ((const float4*)qkv_w)[i];
    ushort4 o = { f2bf(v.x), f2bf(v.y), f2bf(v.z), f2bf(v.w) };
    ((ushort4*)qkv_wb)[i] = o;
  }
  const int np4 = (DIM * DIM) / 4;
  for (int i = tid; i < np4; i += nthr) {
    float4 v = ((const float4*)proj_w)[i];
    ushort4 o = { f2bf(v.x), f2bf(v.y), f2bf(v.z), f2bf(v.w) };
    ((ushort4*)proj_wb)[i] = o;
  }
  // biasP: 12 heads * 16 tiles * 64 lanes float4s = 12288 float4
  for (int i = tid; i < 12288; i += nthr) {
    const int lane = i & 63;
    const int t    = (i >> 6) & 15;
    const int h    = i >> 10;
    const int rb   = (t >> 2) * 16 + (lane >> 4) * 4;
    const int c    = (t & 3) * 16 + (lane & 15);
    float4 o;
    float* op = (float*)&o;
#pragma unroll
    for (int reg = 0; reg < 4; reg++) {
      const int r = rb + reg;
      op[reg] = (r < NTOK && c < NTOK)
                  ? rel_table[rel_index[r * NTOK + c] * HEADS + h]
                  : -1e30f;
    }
    ((float4*)biasP)[i] = o;
  }
  // maskP: 64 groups * 16 tiles * 64 lanes float4s = 65536 float4
  for (int i = tid; i < 65536; i += nthr) {
    const int lane = i & 63;
    const int t    = (i >> 6) & 15;
    const int g    = i >> 10;
    const int rb   = (t >> 2) * 16 + (lane >> 4) * 4;
    const int c    = (t & 3) * 16 + (lane & 15);
    float4 o;
    float* op = (float*)&o;
#pragma unroll
    for (int reg = 0; reg < 4; reg++) {
      const int r = rb + reg;
      op[reg] = (r < NTOK && c < NTOK)
                  ? mask[g * (NTOK * NTOK) + r * NTOK + c]
                  : -1e30f;
    }
    ((float4*)maskP)[i] = o;
  }
}

// ---------------------------------------------------------------------------
// gemm_bt: C[M,N] = A[M,K] * W[N,K]^T + bias[N]; bf16 MFMA, fp32 acc.
// Double-buffered LDS (T3-minimum): issue stage(k+1) into buf^1, compute(k)
// from buf, ONE barrier per K-step. Load latency hides under the 16 MFMAs.
// A_FP32=1: A fp32, reg-staged; cvt (HW v_cvt_pk_bf16_f32) + ds_write placed
//           AFTER the MFMAs so the global-load latency is covered.
// A_FP32=0: A bf16 via global_load_lds.
// Grid: 1D, nwg % 8 == 0 REQUIRED (bijective XCD swizzle).
// Epilogue: LDS-transposed so C-stores are full 128B lines.
// ---------------------------------------------------------------------------
template <int OUT_BF16, int A_FP32>
__global__ __launch_bounds__(256, 2)
void gemm_bt(const void* __restrict__ Ap,
             const unsigned short* __restrict__ W,
             const float* __restrict__ bias,
             void* __restrict__ Cout,
             int M, int N, int K) {
  constexpr int ESTR = OUT_BF16 ? 144 : 272;   // epilogue row stride (bytes)
  constexpr int ESZ  = 16 * ESTR;              // one 16x64 tile
  constexpr int LDS_MAIN = 32768;              // 2 x (A 8K | B 8K)
  constexpr int LDS_EPI  = 4 * 2 * ESZ;
  __shared__ __align__(16) char lds[(LDS_MAIN > LDS_EPI) ? LDS_MAIN : LDS_EPI];

  const int tid  = threadIdx.x;
  const int lane = tid & 63;
  const int wave = tid >> 6;
  const int wr   = wave >> 1;
  const int wc   = wave & 1;
  const int q4   = lane >> 4;
  const int lm   = lane & 15;

  // ---- XCD-aware bijective chunked swizzle (T1).
  const int NT  = N >> 7;                 // N/128 tiles
  const int cpx = gridDim.x >> 3;         // nwg/8 (nwg%8==0 by construction)
  const int lin = (blockIdx.x & 7) * cpx + (blockIdx.x >> 3);
  const int tileM = (lin / NT) * 128;     // N-tile cycles fastest within chunk
  const int tileN = (lin % NT) * 128;

  const int srow = tid >> 2;
  const int scol = (tid & 3) * 8;
  const unsigned short* gA = nullptr;
  const float*          gAf = nullptr;
  if constexpr (A_FP32)
    gAf = (const float*)Ap + (size_t)(tileM + srow) * K + scol;
  else
    gA = (const unsigned short*)Ap + (size_t)(tileM + srow) * K + scol;
  const unsigned short* gB = W + (size_t)(tileN + srow) * K + scol;
  const int loff = tid * 16;

  const int aoff = (wr * 64 + lm) * 64 + q4 * 16;
  const int boff = (wc * 64 + lm) * 64 + q4 * 16;

  char* curA = lds;
  char* nxtA = lds + 8192;
  char* curB = lds + 16384;
  char* nxtB = lds + 24576;

  floatx4 acc[4][4] = {};
  float4 pa0, pa1, pa2, pa3;

  // ---- prologue: stage tile 0 into cur buffers ----
  if constexpr (A_FP32) {
    pa0 = *(const float4*)(gAf);
    pa1 = *(const float4*)(gAf + 4);
    pa2 = *(const float4*)(gAf + (size_t)64 * K);
    pa3 = *(const float4*)(gAf + (size_t)64 * K + 4);
    gAf += 32;
    *(uint4*)(curA + loff)        = cvt8(pa0, pa1);
    *(uint4*)(curA + 4096 + loff) = cvt8(pa2, pa3);
  } else {
    async_copy16(gA,          curA + loff);
    async_copy16(gA + 64 * K, curA + 4096 + loff);
    gA += 32;
  }
  async_copy16(gB,          curB + loff);
  async_copy16(gB + 64 * K, curB + 4096 + loff);
  gB += 32;
  __syncthreads();

  for (int k0 = 0; k0 < K; k0 += 32) {
    const bool pref = (k0 + 32 < K);
    // ---- issue next-tile loads first (in flight across the MFMA phase) ----
    if (pref) {
      if constexpr (A_FP32) {
        pa0 = *(const float4*)(gAf);
        pa1 = *(const float4*)(gAf + 4);
        pa2 = *(const float4*)(gAf + (size_t)64 * K);
        pa3 = *(const float4*)(gAf + (size_t)64 * K + 4);
        gAf += 32;
      } else {
        async_copy16(gA,          nxtA + loff);
        async_copy16(gA + 64 * K, nxtA + 4096 + loff);
        gA += 32;
      }
      async_copy16(gB,          nxtB + loff);
      async_copy16(gB + 64 * K, nxtB + 4096 + loff);
      gB += 32;
    }

    // ---- compute current tile ----
    bf16x8 af[4], bfr[4];
#pragma unroll
    for (int i = 0; i < 4; i++) {
      af[i]  = *(const bf16x8*)(curA + aoff + i * 1024);
      bfr[i] = *(const bf16x8*)(curB + boff + i * 1024);
    }
#pragma unroll
    for (int i = 0; i < 4; i++)
#pragma unroll
      for (int j = 0; j < 4; j++)
        acc[i][j] = __builtin_amdgcn_mfma_f32_16x16x32_bf16(af[i], bfr[j], acc[i][j], 0, 0, 0);

    // ---- A fp32: convert + ds_write AFTER MFMAs (vmcnt wait covered) ----
    if constexpr (A_FP32) {
      if (pref) {
        *(uint4*)(nxtA + loff)        = cvt8(pa0, pa1);
        *(uint4*)(nxtA + 4096 + loff) = cvt8(pa2, pa3);
      }
    }
    __syncthreads();   // single barrier per K-step: drains DMA + ds_writes
    char* t;
    t = curA; curA = nxtA; nxtA = t;
    t = curB; curB = nxtB; nxtB = t;
  }
  // All waves past final barrier: LDS reusable as wave-private epilogue scratch.

  float bvj[4];
#pragma unroll
  for (int j = 0; j < 4; j++) bvj[j] = bias[tileN + wc * 64 + j * 16 + lm];

  char* Eb = lds + wave * (2 * ESZ);
#pragma unroll
  for (int i = 0; i < 4; i++) {
    char* Ep = Eb + (i & 1) * ESZ;
    if (OUT_BF16) {
#pragma unroll
      for (int j = 0; j < 4; j++)
#pragma unroll
        for (int r = 0; r < 4; r++)
          *(unsigned short*)(Ep + (q4 * 4 + r) * 144 + (j * 16 + lm) * 2) =
              f2bf(acc[i][j][r] + bvj[j]);
#pragma unroll
      for (int it = 0; it < 2; it++) {
        const int c   = lane + it * 64;
        const int row = c >> 3;
        const int c8  = c & 7;
        const uint4 v = *(const uint4*)(Ep + row * 144 + c8 * 16);
        unsigned short* dst = (unsigned short*)Cout +
            (size_t)(tileM + wr * 64 + i * 16 + row) * N + tileN + wc * 64 + c8 * 8;
        *(uint4*)dst = v;
      }
    } else {
#pragma unroll
      for (int j = 0; j < 4; j++)
#pragma unroll
        for (int r = 0; r < 4; r++)
          *(float*)(Ep + (q4 * 4 + r) * 272 + (j * 16 + lm) * 4) =
              acc[i][j][r] + bvj[j];
#pragma unroll
      for (int it = 0; it < 4; it++) {
        const int c   = lane + it * 64;
        const int row = c >> 4;
        const int c4  = c & 15;
        const uint4 v = *(const uint4*)(Ep + row * 272 + c4 * 16);
        float* dst = (float*)Cout +
            (size_t)(tileM + wr * 64 + i * 16 + row) * N + tileN + wc * 64 + c4 * 4;
        *(uint4*)dst = v;
      }
    }
  }
}

// ---------------------------------------------------------------------------
// attn_mfma: ONE block per (window b, head h); 4 waves cooperate, wave w owns
// row-tile i=w. LDS 16128 B/block -> waves-capped occupancy (8 blocks/CU).
// V staged coalesced + LDS-transposed scatter. Bias+mask are coalesced float4
// loads from precomputed swizzled tables. Softmax w/o max-sub (|S|<~15 << 88).
// Row sums via ones-row in Vt.
// ---------------------------------------------------------------------------
__global__ __launch_bounds__(256, 8)
void attn_mfma(const unsigned short* __restrict__ qkv,
               const float* __restrict__ biasP,
               const float* __restrict__ maskP,
               unsigned short* __restrict__ attn_out) {
  // [0,6912): Vt 48 rows * 144B (rows 0..31 = V^T, row 32 = ones, 33..47 slack)
  // [6912,11008): Q 64*64B ; [11008,15104): K 64*64B
  // P aliases [6912,16128): 64 rows * 144B  (valid: barrier after QK frag reads)
  __shared__ __align__(16) char lds[16128];
  char* Vt = lds;
  char* Qb = lds + 6912;
  char* Kb = lds + 11008;
  char* Pb = lds + 6912;

  const int tid  = threadIdx.x;
  const int wave = tid >> 6;
  const int lane = tid & 63;
  const int lm   = lane & 15;
  const int q    = lane >> 4;

  // T1: XCD-chunked pair index (24576 % 8 == 0): heads of one window share XCD L2
  const int pair = (blockIdx.x & 7) * (NWIN * HEADS / 8) + (blockIdx.x >> 3);
  const int b    = pair / HEADS;
  const int h    = pair - b * HEADS;
  const int g    = b & (NMASK - 1);

  const unsigned short* qbase = qkv + (size_t)b * NTOK * (3 * DIM) + h * HD;

  // ---- cooperative stage: Q,K row-major (zero-padded rows>=49) ----
  {
    const int row   = tid >> 2;
    const int chunk = tid & 3;
    uint4 vq = {0u, 0u, 0u, 0u}, vk = vq;
    if (row < NTOK) {
      vq = *(const uint4*)(qbase + (size_t)row * (3 * DIM) + chunk * 8);
      vk = *(const uint4*)(qbase + (size_t)row * (3 * DIM) + DIM + chunk * 8);
    }
    *(uint4*)(Qb + row * 64 + chunk * 16) = vq;
    *(uint4*)(Kb + row * 64 + chunk * 16) = vk;
  }
  // ---- cooperative stage V: coalesced load + transposed LDS scatter ----
  {
    const int tok = tid >> 2;
    const int c   = tid & 3;
    uint4 vv = {0u, 0u, 0u, 0u};
    if (tok < NTOK) vv = *(const uint4*)(qbase + 2 * DIM + (size_t)tok * (3 * DIM) + c * 8);
    const unsigned short* e = (const unsigned short*)&vv;
#pragma unroll
    for (int j = 0; j < 8; j++)
      *(unsigned short*)(Vt + (c * 8 + j) * 144 + tok * 2) = e[j];
    if (tid < 64)  // ones row for row-sum trick
      *(unsigned short*)(Vt + HD * 144 + tid * 2) =
          (tid < NTOK) ? (unsigned short)0x3F80 : (unsigned short)0;
  }
  __syncthreads();

  // ---- QK^T: wave w computes S rows [w*16, w*16+16) ----
  bf16x8 qf, kf[4];
  qf = *(const bf16x8*)(Qb + (wave * 16 + lm) * 64 + q * 16);
#pragma unroll
  for (int j = 0; j < 4; j++)
    kf[j] = *(const bf16x8*)(Kb + (j * 16 + lm) * 64 + q * 16);
  floatx4 S[4] = {};
#pragma unroll
  for (int j = 0; j < 4; j++)
    S[j] = __builtin_amdgcn_mfma_f32_16x16x32_bf16(qf, kf[j], S[j], 0, 0, 0);

  __syncthreads();  // all Q/K LDS reads done in all waves: P may overwrite

  // ---- softmax + P (bf16) into own rows of LDS ----
  const float scale = 0.17677669529663687f;  // 32^-0.5
  const float* bb = biasP + (size_t)h * 4096;
  const float* mm = maskP + (size_t)g * 4096;
#pragma unroll
  for (int j = 0; j < 4; j++) {
    const int t = wave * 4 + j;
    const float4 b4 = ((const float4*)bb)[t * 64 + lane];
    const float4 m4 = ((const float4*)mm)[t * 64 + lane];
    const float* bp = (const float*)&b4;
    const float* mp = (const float*)&m4;
#pragma unroll
    for (int r = 0; r < 4; r++) {
      const float s = fmaf(S[j][r], scale, bp[r] + mp[r]);
      const float p = __expf(s);
      *(unsigned short*)(Pb + (wave * 16 + q * 4 + r) * 144 + (j * 16 + lm) * 2) = f2bf(p);
    }
  }

  // ---- PV: wave reads ONLY its own P rows (same-wave lgkm ordering, no barrier)
  floatx4 O[3] = {};
#pragma unroll
  for (int ks = 0; ks < 2; ks++) {
    const bf16x8 pf = *(const bf16x8*)(Pb + (wave * 16 + lm) * 144 + ks * 64 + q * 16);
#pragma unroll
    for (int n = 0; n < 3; n++) {
      const bf16x8 vf = *(const bf16x8*)(Vt + (n * 16 + lm) * 144 + ks * 64 + q * 16);
      O[n] = __builtin_amdgcn_mfma_f32_16x16x32_bf16(pf, vf, O[n], 0, 0, 0);
    }
  }

  // ---- epilogue: divide by row sum (O[2] col 32, lanes with lm==0), store ----
  unsigned short* obase = attn_out + (size_t)b * NTOK * DIM + h * HD;
#pragma unroll
  for (int r = 0; r < 4; r++) {
    const float sv  = __shfl(O[2][r], lane & 48, 64);
    const float inv = __builtin_amdgcn_rcpf(sv);
    const int row = wave * 16 + q * 4 + r;
    if (row < NTOK) {
#pragma unroll
      for (int n = 0; n < 2; n++)
        obase[(size_t)row * DIM + n * 16 + lm] = f2bf(O[n][r] * inv);
    }
  }
}

// ---------------------------------------------------------------------------
// launch
// ---------------------------------------------------------------------------
extern "C" void kernel_launch(void* const* d_in, const int* in_sizes, int n_in,
                              void* d_out, int out_size, void* d_ws, size_t ws_size,
                              hipStream_t stream) {
  const float* x         = (const float*)d_in[0];
  const float* mask      = (const float*)d_in[1];
  const float* qkv_w     = (const float*)d_in[2];
  const float* qkv_b     = (const float*)d_in[3];
  const float* proj_w    = (const float*)d_in[4];
  const float* proj_b    = (const float*)d_in[5];
  const float* rel_table = (const float*)d_in[6];
  const int*   rel_index = (const int*)d_in[7];
  float* out = (float*)d_out;

  char* ws = (char*)d_ws;
  unsigned short* attn_o  = (unsigned short*)(ws);                 // 77,070,336 B (scratch)
  unsigned short* qkvbuf  = (unsigned short*)(ws + 77070336);      // 231,211,008 B
  unsigned short* qkv_wb  = (unsigned short*)(ws + 308281344);     // 884,736 B
  unsigned short* proj_wb = (unsigned short*)(ws + 309166080);     // 294,912 B
  float*          biasP   = (float*)(ws + 309460992);              // 196,608 B
  float*          maskP   = (float*)(ws + 309657600);              // 1,048,576 B

  prep_kernel<<<768, 256, 0, stream>>>(qkv_w, proj_w, rel_table, rel_index,
                                       mask, qkv_wb, proj_wb, biasP, maskP);

  // nwg = 784*9 = 7056 (%8==0) and 784*3 = 2352 (%8==0): bijective T1 swizzle ok
  gemm_bt<1, 1><<<dim3((MTOT / 128) * ((3 * DIM) / 128)), 256, 0, stream>>>(
      x, qkv_wb, qkv_b, qkvbuf, MTOT, 3 * DIM, DIM);

  attn_mfma<<<dim3(NWIN * HEADS), 256, 0, stream>>>(qkvbuf, biasP, maskP,
                                                    attn_o);

  gemm_bt<0, 0><<<dim3((MTOT / 128) * (DIM / 128)), 256, 0, stream>>>(
      attn_o, proj_wb, proj_b, out, MTOT, DIM, DIM);
}

// Round 5
// 542.338 us; speedup vs baseline: 1.0431x; 1.0431x over previous
//
#include <hip/hip_runtime.h>

#define DIM   384
#define HEADS 12
#define NTOK  49
#define NWIN  2048
#define NMASK 64
#define HD    32
#define MTOT  (NWIN * NTOK)   // 100352

typedef __bf16 bf16x8 __attribute__((ext_vector_type(8)));
typedef float  floatx4 __attribute__((ext_vector_type(4)));

__device__ __forceinline__ unsigned short f2bf(float f) {
  unsigned int u = __builtin_bit_cast(unsigned int, f);
  u += 0x7fffu + ((u >> 16) & 1u);   // RNE
  return (unsigned short)(u >> 16);
}
// 8 fp32 -> bf16x8 via HW cvt (compiler pairs into v_cvt_pk_bf16_f32)
__device__ __forceinline__ bf16x8 cvt8f(float4 a, float4 b) {
  bf16x8 r;
  r[0] = (__bf16)a.x; r[1] = (__bf16)a.y; r[2] = (__bf16)a.z; r[3] = (__bf16)a.w;
  r[4] = (__bf16)b.x; r[5] = (__bf16)b.y; r[6] = (__bf16)b.z; r[7] = (__bf16)b.w;
  return r;
}
__device__ __forceinline__ void async_copy16(const void* g, void* l) {
  __builtin_amdgcn_global_load_lds((const __attribute__((address_space(1))) void*)g,
                                   (__attribute__((address_space(3))) void*)l, 16, 0, 0);
}

// ---------------------------------------------------------------------------
// prep: weight fp32->bf16 converts + lane-swizzled padded bias/mask tables.
// (x is consumed fp32 directly by the QKV gemm.)
// biasP[h][tile t][lane][reg] : r = (t>>2)*16 + (lane>>4)*4 + reg,
//                               c = (t&3)*16 + (lane&15); pad(-1e30) if r/c>=49
// maskP[g][...] identical layout.
// ---------------------------------------------------------------------------
__global__ void prep_kernel(const float* __restrict__ qkv_w,
                            const float* __restrict__ proj_w,
                            const float* __restrict__ rel_table,
                            const int*   __restrict__ rel_index,
                            const float* __restrict__ mask,
                            unsigned short* __restrict__ qkv_wb,
                            unsigned short* __restrict__ proj_wb,
                            float* __restrict__ biasP,
                            float* __restrict__ maskP) {
  const int tid  = blockIdx.x * blockDim.x + threadIdx.x;
  const int nthr = gridDim.x * blockDim.x;

  const int nw4 = (3 * DIM * DIM) / 4;
  for (int i = tid; i < nw4; i += nthr) {
    float4 v = ((const float4*)qkv_w)[i];
    ushort4 o = { f2bf(v.x), f2bf(v.y), f2bf(v.z), f2bf(v.w) };
    ((ushort4*)qkv_wb)[i] = o;
  }
  const int np4 = (DIM * DIM) / 4;
  for (int i = tid; i < np4; i += nthr) {
    float4 v = ((const float4*)proj_w)[i];
    ushort4 o = { f2bf(v.x), f2bf(v.y), f2bf(v.z), f2bf(v.w) };
    ((ushort4*)proj_wb)[i] = o;
  }
  // biasP: 12 heads * 16 tiles * 64 lanes float4s = 12288 float4
  for (int i = tid; i < 12288; i += nthr) {
    const int lane = i & 63;
    const int t    = (i >> 6) & 15;
    const int h    = i >> 10;
    const int rb   = (t >> 2) * 16 + (lane >> 4) * 4;
    const int c    = (t & 3) * 16 + (lane & 15);
    float4 o;
    float* op = (float*)&o;
#pragma unroll
    for (int reg = 0; reg < 4; reg++) {
      const int r = rb + reg;
      op[reg] = (r < NTOK && c < NTOK)
                  ? rel_table[rel_index[r * NTOK + c] * HEADS + h]
                  : -1e30f;
    }
    ((float4*)biasP)[i] = o;
  }
  // maskP: 64 groups * 16 tiles * 64 lanes float4s = 65536 float4
  for (int i = tid; i < 65536; i += nthr) {
    const int lane = i & 63;
    const int t    = (i >> 6) & 15;
    const int g    = i >> 10;
    const int rb   = (t >> 2) * 16 + (lane >> 4) * 4;
    const int c    = (t & 3) * 16 + (lane & 15);
    float4 o;
    float* op = (float*)&o;
#pragma unroll
    for (int reg = 0; reg < 4; reg++) {
      const int r = rb + reg;
      op[reg] = (r < NTOK && c < NTOK)
                  ? mask[g * (NTOK * NTOK) + r * NTOK + c]
                  : -1e30f;
    }
    ((float4*)maskP)[i] = o;
  }
}

// ---------------------------------------------------------------------------
// gemm_bt: C[M,N] = A[M,K] * W[N,K]^T + bias[N]; bf16 MFMA, fp32 acc.
// Round-1 proven structure: single LDS buffer pair, stage-all-DMA, 2 barriers
// per K-step (reg-prefetch across __syncthreads is a proven anti-pattern:
// the barrier's vmcnt(0) drain force-retires it -- rounds 2/3 evidence).
// A_FP32=1: A staged fp32 via global_load_lds with XOR-SWIZZLED SOURCE
//   (LDS dest linear; LDS(row,g)=G(row,g^(row&7)), granule=16B). Frag read:
//   2x ds_read_b128 (conflict-free by the swizzle) + cvt8f -> bf16 frag.
// A_FP32=0: A bf16 via global_load_lds (linear), unchanged.
// Grid: 1D, nwg % 8 == 0 REQUIRED (bijective XCD swizzle).
// Epilogue: LDS-transposed so C-stores are full 128B lines.
// ---------------------------------------------------------------------------
template <int OUT_BF16, int A_FP32>
__global__ __launch_bounds__(256, 2)
void gemm_bt(const void* __restrict__ Ap,
             const unsigned short* __restrict__ W,
             const float* __restrict__ bias,
             void* __restrict__ Cout,
             int M, int N, int K) {
  constexpr int ESTR = OUT_BF16 ? 144 : 272;     // epilogue row stride (bytes)
  constexpr int ESZ  = 16 * ESTR;                // one 16x64 tile
  constexpr int ABYTES   = A_FP32 ? 16384 : 8192;  // A tile bytes in LDS
  constexpr int LDS_MAIN = ABYTES + 8192;
  constexpr int LDS_EPI  = 4 * 2 * ESZ;
  __shared__ __align__(16) char lds[(LDS_MAIN > LDS_EPI) ? LDS_MAIN : LDS_EPI];
  char* ldsA = lds;
  char* ldsB = lds + ABYTES;

  const int tid  = threadIdx.x;
  const int lane = tid & 63;
  const int wave = tid >> 6;
  const int wr   = wave >> 1;
  const int wc   = wave & 1;
  const int q4   = lane >> 4;
  const int lm   = lane & 15;

  // ---- XCD-aware bijective chunked swizzle (T1).
  const int NT  = N >> 7;                 // N/128 tiles
  const int cpx = gridDim.x >> 3;         // nwg/8 (nwg%8==0 by construction)
  const int lin = (blockIdx.x & 7) * cpx + (blockIdx.x >> 3);
  const int tileM = (lin / NT) * 128;     // N-tile cycles fastest within chunk
  const int tileN = (lin % NT) * 128;

  const int srow = tid >> 2;
  const int scol = (tid & 3) * 8;
  const unsigned short* gA = nullptr;
  const float* gac[4];
  if constexpr (A_FP32) {
    // 4 DMA copies/thread/step; slot s = c*256+tid; row=s>>3, g=s&7;
    // source granule gg = g ^ (row&7)  (bank-conflict-free frag reads)
#pragma unroll
    for (int c = 0; c < 4; c++) {
      const int s   = c * 256 + tid;
      const int row = s >> 3;
      const int gg  = (s & 7) ^ (row & 7);
      gac[c] = (const float*)Ap + (size_t)(tileM + row) * K + gg * 4;
    }
  } else {
    gA = (const unsigned short*)Ap + (size_t)(tileM + srow) * K + scol;
  }
  const unsigned short* gB = W + (size_t)(tileN + srow) * K + scol;
  const int loff = tid * 16;

  const int aoff = (wr * 64 + lm) * 64 + q4 * 16;   // bf16-A frag offset
  const int boff = (wc * 64 + lm) * 64 + q4 * 16;
  const int x7   = lm & 7;                          // fp32-A read XOR key

  floatx4 acc[4][4] = {};

  for (int k0 = 0; k0 < K; k0 += 32) {
    if constexpr (A_FP32) {
#pragma unroll
      for (int c = 0; c < 4; c++)
        async_copy16(gac[c] + k0, ldsA + c * 4096 + loff);
    } else {
      async_copy16(gA,          ldsA + loff);
      async_copy16(gA + 64 * K, ldsA + 4096 + loff);
      gA += 32;
    }
    async_copy16(gB,          ldsB + loff);
    async_copy16(gB + 64 * K, ldsB + 4096 + loff);
    gB += 32;
    __syncthreads();

    bf16x8 af[4], bfr[4];
#pragma unroll
    for (int i = 0; i < 4; i++) {
      if constexpr (A_FP32) {
        const int r = wr * 64 + i * 16 + lm;
        const float4 fa = *(const float4*)(ldsA + r * 128 + (((2 * q4)    ) ^ x7) * 16);
        const float4 fb = *(const float4*)(ldsA + r * 128 + (((2 * q4) | 1) ^ x7) * 16);
        af[i] = cvt8f(fa, fb);
      } else {
        af[i] = *(const bf16x8*)(ldsA + aoff + i * 1024);
      }
      bfr[i] = *(const bf16x8*)(ldsB + boff + i * 1024);
    }
#pragma unroll
    for (int i = 0; i < 4; i++)
#pragma unroll
      for (int j = 0; j < 4; j++)
        acc[i][j] = __builtin_amdgcn_mfma_f32_16x16x32_bf16(af[i], bfr[j], acc[i][j], 0, 0, 0);
    __syncthreads();
  }
  // All waves past final barrier: LDS reusable as wave-private epilogue scratch.

  float bvj[4];
#pragma unroll
  for (int j = 0; j < 4; j++) bvj[j] = bias[tileN + wc * 64 + j * 16 + lm];

  char* Eb = lds + wave * (2 * ESZ);
#pragma unroll
  for (int i = 0; i < 4; i++) {
    char* Ep = Eb + (i & 1) * ESZ;
    if (OUT_BF16) {
#pragma unroll
      for (int j = 0; j < 4; j++)
#pragma unroll
        for (int r = 0; r < 4; r++)
          *(unsigned short*)(Ep + (q4 * 4 + r) * 144 + (j * 16 + lm) * 2) =
              f2bf(acc[i][j][r] + bvj[j]);
#pragma unroll
      for (int it = 0; it < 2; it++) {
        const int c   = lane + it * 64;
        const int row = c >> 3;
        const int c8  = c & 7;
        const uint4 v = *(const uint4*)(Ep + row * 144 + c8 * 16);
        unsigned short* dst = (unsigned short*)Cout +
            (size_t)(tileM + wr * 64 + i * 16 + row) * N + tileN + wc * 64 + c8 * 8;
        *(uint4*)dst = v;
      }
    } else {
#pragma unroll
      for (int j = 0; j < 4; j++)
#pragma unroll
        for (int r = 0; r < 4; r++)
          *(float*)(Ep + (q4 * 4 + r) * 272 + (j * 16 + lm) * 4) =
              acc[i][j][r] + bvj[j];
#pragma unroll
      for (int it = 0; it < 4; it++) {
        const int c   = lane + it * 64;
        const int row = c >> 4;
        const int c4  = c & 15;
        const uint4 v = *(const uint4*)(Ep + row * 272 + c4 * 16);
        float* dst = (float*)Cout +
            (size_t)(tileM + wr * 64 + i * 16 + row) * N + tileN + wc * 64 + c4 * 4;
        *(uint4*)dst = v;
      }
    }
  }
}

// ---------------------------------------------------------------------------
// attn_mfma: ONE block per (window b, head h); 4 waves cooperate, wave w owns
// row-tile i=w. LDS 16128 B/block -> waves-capped occupancy (8 blocks/CU).
// V staged coalesced + LDS-transposed scatter. Bias+mask are coalesced float4
// loads from precomputed swizzled tables. Softmax w/o max-sub (|S|<~15 << 88).
// Row sums via ones-row in Vt.
// ---------------------------------------------------------------------------
__global__ __launch_bounds__(256, 8)
void attn_mfma(const unsigned short* __restrict__ qkv,
               const float* __restrict__ biasP,
               const float* __restrict__ maskP,
               unsigned short* __restrict__ attn_out) {
  // [0,6912): Vt 48 rows * 144B (rows 0..31 = V^T, row 32 = ones, 33..47 slack)
  // [6912,11008): Q 64*64B ; [11008,15104): K 64*64B
  // P aliases [6912,16128): 64 rows * 144B  (valid: barrier after QK frag reads)
  __shared__ __align__(16) char lds[16128];
  char* Vt = lds;
  char* Qb = lds + 6912;
  char* Kb = lds + 11008;
  char* Pb = lds + 6912;

  const int tid  = threadIdx.x;
  const int wave = tid >> 6;
  const int lane = tid & 63;
  const int lm   = lane & 15;
  const int q    = lane >> 4;

  // T1: XCD-chunked pair index (24576 % 8 == 0): heads of one window share XCD L2
  const int pair = (blockIdx.x & 7) * (NWIN * HEADS / 8) + (blockIdx.x >> 3);
  const int b    = pair / HEADS;
  const int h    = pair - b * HEADS;
  const int g    = b & (NMASK - 1);

  const unsigned short* qbase = qkv + (size_t)b * NTOK * (3 * DIM) + h * HD;

  // ---- cooperative stage: Q,K row-major (zero-padded rows>=49) ----
  {
    const int row   = tid >> 2;
    const int chunk = tid & 3;
    uint4 vq = {0u, 0u, 0u, 0u}, vk = vq;
    if (row < NTOK) {
      vq = *(const uint4*)(qbase + (size_t)row * (3 * DIM) + chunk * 8);
      vk = *(const uint4*)(qbase + (size_t)row * (3 * DIM) + DIM + chunk * 8);
    }
    *(uint4*)(Qb + row * 64 + chunk * 16) = vq;
    *(uint4*)(Kb + row * 64 + chunk * 16) = vk;
  }
  // ---- cooperative stage V: coalesced load + transposed LDS scatter ----
  {
    const int tok = tid >> 2;
    const int c   = tid & 3;
    uint4 vv = {0u, 0u, 0u, 0u};
    if (tok < NTOK) vv = *(const uint4*)(qbase + 2 * DIM + (size_t)tok * (3 * DIM) + c * 8);
    const unsigned short* e = (const unsigned short*)&vv;
#pragma unroll
    for (int j = 0; j < 8; j++)
      *(unsigned short*)(Vt + (c * 8 + j) * 144 + tok * 2) = e[j];
    if (tid < 64)  // ones row for row-sum trick
      *(unsigned short*)(Vt + HD * 144 + tid * 2) =
          (tid < NTOK) ? (unsigned short)0x3F80 : (unsigned short)0;
  }
  __syncthreads();

  // ---- QK^T: wave w computes S rows [w*16, w*16+16) ----
  bf16x8 qf, kf[4];
  qf = *(const bf16x8*)(Qb + (wave * 16 + lm) * 64 + q * 16);
#pragma unroll
  for (int j = 0; j < 4; j++)
    kf[j] = *(const bf16x8*)(Kb + (j * 16 + lm) * 64 + q * 16);
  floatx4 S[4] = {};
#pragma unroll
  for (int j = 0; j < 4; j++)
    S[j] = __builtin_amdgcn_mfma_f32_16x16x32_bf16(qf, kf[j], S[j], 0, 0, 0);

  __syncthreads();  // all Q/K LDS reads done in all waves: P may overwrite

  // ---- softmax + P (bf16) into own rows of LDS ----
  const float scale = 0.17677669529663687f;  // 32^-0.5
  const float* bb = biasP + (size_t)h * 4096;
  const float* mm = maskP + (size_t)g * 4096;
#pragma unroll
  for (int j = 0; j < 4; j++) {
    const int t = wave * 4 + j;
    const float4 b4 = ((const float4*)bb)[t * 64 + lane];
    const float4 m4 = ((const float4*)mm)[t * 64 + lane];
    const float* bp = (const float*)&b4;
    const float* mp = (const float*)&m4;
#pragma unroll
    for (int r = 0; r < 4; r++) {
      const float s = fmaf(S[j][r], scale, bp[r] + mp[r]);
      const float p = __expf(s);
      *(unsigned short*)(Pb + (wave * 16 + q * 4 + r) * 144 + (j * 16 + lm) * 2) = f2bf(p);
    }
  }

  // ---- PV: wave reads ONLY its own P rows (same-wave lgkm ordering, no barrier)
  floatx4 O[3] = {};
#pragma unroll
  for (int ks = 0; ks < 2; ks++) {
    const bf16x8 pf = *(const bf16x8*)(Pb + (wave * 16 + lm) * 144 + ks * 64 + q * 16);
#pragma unroll
    for (int n = 0; n < 3; n++) {
      const bf16x8 vf = *(const bf16x8*)(Vt + (n * 16 + lm) * 144 + ks * 64 + q * 16);
      O[n] = __builtin_amdgcn_mfma_f32_16x16x32_bf16(pf, vf, O[n], 0, 0, 0);
    }
  }

  // ---- epilogue: divide by row sum (O[2] col 32, lanes with lm==0), store ----
  unsigned short* obase = attn_out + (size_t)b * NTOK * DIM + h * HD;
#pragma unroll
  for (int r = 0; r < 4; r++) {
    const float sv  = __shfl(O[2][r], lane & 48, 64);
    const float inv = __builtin_amdgcn_rcpf(sv);
    const int row = wave * 16 + q * 4 + r;
    if (row < NTOK) {
#pragma unroll
      for (int n = 0; n < 2; n++)
        obase[(size_t)row * DIM + n * 16 + lm] = f2bf(O[n][r] * inv);
    }
  }
}

// ---------------------------------------------------------------------------
// launch
// ---------------------------------------------------------------------------
extern "C" void kernel_launch(void* const* d_in, const int* in_sizes, int n_in,
                              void* d_out, int out_size, void* d_ws, size_t ws_size,
                              hipStream_t stream) {
  const float* x         = (const float*)d_in[0];
  const float* mask      = (const float*)d_in[1];
  const float* qkv_w     = (const float*)d_in[2];
  const float* qkv_b     = (const float*)d_in[3];
  const float* proj_w    = (const float*)d_in[4];
  const float* proj_b    = (const float*)d_in[5];
  const float* rel_table = (const float*)d_in[6];
  const int*   rel_index = (const int*)d_in[7];
  float* out = (float*)d_out;

  char* ws = (char*)d_ws;
  unsigned short* attn_o  = (unsigned short*)(ws);                 // 77,070,336 B (scratch)
  unsigned short* qkvbuf  = (unsigned short*)(ws + 77070336);      // 231,211,008 B
  unsigned short* qkv_wb  = (unsigned short*)(ws + 308281344);     // 884,736 B
  unsigned short* proj_wb = (unsigned short*)(ws + 309166080);     // 294,912 B
  float*          biasP   = (float*)(ws + 309460992);              // 196,608 B
  float*          maskP   = (float*)(ws + 309657600);              // 1,048,576 B

  prep_kernel<<<768, 256, 0, stream>>>(qkv_w, proj_w, rel_table, rel_index,
                                       mask, qkv_wb, proj_wb, biasP, maskP);

  // nwg = 784*9 = 7056 (%8==0) and 784*3 = 2352 (%8==0): bijective T1 swizzle ok
  gemm_bt<1, 1><<<dim3((MTOT / 128) * ((3 * DIM) / 128)), 256, 0, stream>>>(
      x, qkv_wb, qkv_b, qkvbuf, MTOT, 3 * DIM, DIM);

  attn_mfma<<<dim3(NWIN * HEADS), 256, 0, stream>>>(qkvbuf, biasP, maskP,
                                                    attn_o);

  gemm_bt<0, 0><<<dim3((MTOT / 128) * (DIM / 128)), 256, 0, stream>>>(
      attn_o, proj_wb, proj_b, out, MTOT, DIM, DIM);
}